// Round 2
// baseline (180.035 us; speedup 1.0000x reference)
//
#include <hip/hip_runtime.h>
#include <hip/hip_bf16.h>
#include <cstdint>

// Problem: B=32, S=1024, H_IN=1024, H=1024
// scores[b,s] = sum_h tanh( enc[b,s,:]·W1_enc[h,:] + hidden[b,:]·W1_hid[h,:] + b1[h] ) * W2[h]  (+b2, softmax-invariant)
// out[b,0,s] = softmax_s( mask ? -inf : scores )

#define BM 128
#define BN 128
#define BK 64

typedef short  s16x8 __attribute__((ext_vector_type(8)));
typedef float  f32x4 __attribute__((ext_vector_type(4)));
typedef unsigned int u32;
typedef unsigned short u16;

__device__ static inline u32 f2bf(float f) {            // f32 -> bf16 (RNE)
    u32 u = __float_as_uint(f);
    return (u + 0x7fffu + ((u >> 16) & 1u)) >> 16;
}
__device__ static inline u32 pk2(float a, float b) {    // two bf16 packed
    return f2bf(a) | (f2bf(b) << 16);
}

__device__ static inline void gload_lds16(const void* g, void* l) {
    __builtin_amdgcn_global_load_lds(
        (const __attribute__((address_space(1))) u32*)g,
        (__attribute__((address_space(3))) u32*)l, 16, 0, 0);
}

// ---------------- pack W1_enc (H x H_IN slice of W1) to bf16, linear [n][k] ----------------
__global__ __launch_bounds__(256) void pack_k(const float* __restrict__ W1, u16* __restrict__ Wb) {
    const size_t i = (size_t)blockIdx.x * 256 + threadIdx.x;   // float4 index, total 262144
    const size_t n = (i * 4) >> 10, k = (i * 4) & 1023;
    const float4 v = *(const float4*)(W1 + n * 2048 + k);
    uint2 p; p.x = pk2(v.x, v.y); p.y = pk2(v.z, v.w);
    ((uint2*)Wb)[i] = p;
}

// ---------------- hv[b][h] = hidden[b,:]·W1_hid[h,:] + b1[h]  (f32, exact) ----------------
__global__ __launch_bounds__(256) void hv_k(const float* __restrict__ hidden,
                                            const float* __restrict__ W1,
                                            const float* __restrict__ b1,
                                            float* __restrict__ hv) {
    const int wid = threadIdx.x >> 6, lane = threadIdx.x & 63;
    const int h = blockIdx.x * 4 + wid;
    const float4* wrow = (const float4*)(W1 + (size_t)h * 2048 + 1024);
    float4 w[4];
#pragma unroll
    for (int q = 0; q < 4; q++) w[q] = wrow[lane + 64 * q];
    for (int b = 0; b < 32; b++) {
        const float4* hb = (const float4*)(hidden + (size_t)b * 1024);
        float p = 0.f;
#pragma unroll
        for (int q = 0; q < 4; q++) {
            float4 x = hb[lane + 64 * q];
            p = fmaf(w[q].x, x.x, fmaf(w[q].y, x.y, fmaf(w[q].z, x.z, fmaf(w[q].w, x.w, p))));
        }
#pragma unroll
        for (int off = 1; off < 64; off <<= 1) p += __shfl_xor(p, off);
        if (lane == 0) hv[(size_t)b * 1024 + h] = p + b1[h];
    }
}

// ---------------- fused GEMM: C = enc(M=32768,K=1024) x Wb^T(N=1024), epilogue tanh·w2 rowsum ----------------
__global__ __launch_bounds__(256, 2) void gemm_fused(
    const float* __restrict__ enc,      // (S,B,HIN) f32
    const u16*   __restrict__ Wb,       // (H, HIN) bf16 packed
    const float* __restrict__ hv,       // (B,H) f32
    const float* __restrict__ W2,       // (H) f32
    float*       __restrict__ scores)   // (B*S) f32, pre-zeroed, atomic accumulate
{
    __shared__ u16 As[2][BM * BK];
    __shared__ u16 Bs[2][BM * BK];

    const int tid = threadIdx.x;
    const int bid = blockIdx.x;
    // XCD swizzle: all 8 n-tiles of an m-strip land on one XCD (A-strip L2 reuse)
    const int xcd = bid & 7, slot = bid >> 3;
    const int mt = xcd * 32 + (slot >> 3), nt = slot & 7;
    const int b = mt >> 3;                       // batch of this m-strip (128 | 1024)

    // A staging: thread t, iter j: row = (t>>4)+j*16, 16B chunk (t&15)
    const int ar = tid >> 4, ac = tid & 15;
    const int s0 = ((mt & 7) << 7) + ar;         // s of this thread's base row
    const float4* aptr4 = (const float4*)(enc + ((size_t)s0 * 32 + b) * 1024) + ac;
    const size_t astr4 = (size_t)16 * 32 * 1024 / 4;   // +16 rows (s+=16) in float4 units

    // B staging via global_load_lds: chunk = j*256+tid; row = j*32+(tid>>3), c16 = tid&7
    const u16* wsrc = Wb + ((size_t)(nt * BN) + (tid >> 3)) * 1024 + (tid & 7) * 8;

    const int wid = tid >> 6, lane = tid & 63;
    const int wr = wid >> 1, wc = wid & 1;
    const int lhi = lane >> 4, llo = lane & 15;

    f32x4 acc[4][4] = {};
    float4 av[8];

    // ---- prologue: stage k-step 0 ----
#pragma unroll
    for (int j = 0; j < 8; j++) av[j] = aptr4[(size_t)j * astr4];
#pragma unroll
    for (int j = 0; j < 4; j++)
        gload_lds16(wsrc + (size_t)j * 32 * 1024, &Bs[0][(j * 256 + tid) * 8]);
#pragma unroll
    for (int j = 0; j < 8; j++) {
        uint2 p; p.x = pk2(av[j].x, av[j].y); p.y = pk2(av[j].z, av[j].w);
        *(uint2*)&As[0][(ar + j * 16) * BK + ac * 4] = p;
    }
    __syncthreads();

    int buf = 0;
    for (int kt = 0; kt < 16; kt++) {
        const int nk = kt + 1;
        if (nk < 16) {
            // issue next-tile loads (in flight across compute)
#pragma unroll
            for (int j = 0; j < 8; j++) av[j] = aptr4[(size_t)j * astr4 + (size_t)nk * 16];
#pragma unroll
            for (int j = 0; j < 4; j++)
                gload_lds16(wsrc + (size_t)nk * 64 + (size_t)j * 32 * 1024,
                            &Bs[buf ^ 1][(j * 256 + tid) * 8]);
        }
        // compute on current buffers
#pragma unroll
        for (int kk = 0; kk < 2; kk++) {
            s16x8 af[4], bfr[4];
#pragma unroll
            for (int f = 0; f < 4; f++)
                af[f] = *(const s16x8*)&As[buf][(wr * 64 + f * 16 + llo) * BK + kk * 32 + lhi * 8];
#pragma unroll
            for (int f = 0; f < 4; f++)
                bfr[f] = *(const s16x8*)&Bs[buf][(wc * 64 + f * 16 + llo) * BK + kk * 32 + lhi * 8];
#pragma unroll
            for (int fi = 0; fi < 4; fi++)
#pragma unroll
                for (int fj = 0; fj < 4; fj++)
                    acc[fi][fj] = __builtin_amdgcn_mfma_f32_16x16x32_bf16(af[fi], bfr[fj], acc[fi][fj], 0, 0, 0);
        }
        if (nk < 16) {
#pragma unroll
            for (int j = 0; j < 8; j++) {
                uint2 p; p.x = pk2(av[j].x, av[j].y); p.y = pk2(av[j].z, av[j].w);
                *(uint2*)&As[buf ^ 1][(ar + j * 16) * BK + ac * 4] = p;
            }
        }
        __syncthreads();
        buf ^= 1;
    }

    // ---- epilogue: tanh(acc + hv) · w2, reduce over this block's 128 n-cols, atomic into scores ----
    const float* hvb = hv + (size_t)b * 1024;
    float hvv[4], w2v[4];
#pragma unroll
    for (int fj = 0; fj < 4; fj++) {
        const int n = nt * BN + wc * 64 + fj * 16 + llo;
        hvv[fj] = hvb[n];
        w2v[fj] = W2[n];
    }
#pragma unroll
    for (int fi = 0; fi < 4; fi++) {
#pragma unroll
        for (int r = 0; r < 4; r++) {
            float sum = 0.f;
#pragma unroll
            for (int fj = 0; fj < 4; fj++) {
                const float x = acc[fi][fj][r] + hvv[fj];
                const float e = __expf(2.f * x);
                const float t = 1.f - 2.f / (e + 1.f);   // tanh(x)
                sum = fmaf(t, w2v[fj], sum);
            }
            sum += __shfl_xor(sum, 1);
            sum += __shfl_xor(sum, 2);
            sum += __shfl_xor(sum, 4);
            sum += __shfl_xor(sum, 8);
            if (llo == 0)
                atomicAdd(&scores[(size_t)mt * BM + wr * 64 + fi * 16 + lhi * 4 + r], sum);
        }
    }
}

// ---------------- masked softmax per row b, mask dtype auto-detected (int32 vs uint8) ----------------
// Detection: scan first 8192 u32 words (=32768 B, in-bounds under both layouts).
// bool->int32 gives words in {0,1}; packed uint8 0/1 bytes give words like 0x00010001 (>1).
__global__ __launch_bounds__(256) void softmax_k(const float* __restrict__ scores,
                                                 const void* __restrict__ maskv,
                                                 float* __restrict__ out) {
    const int b = blockIdx.x, t = threadIdx.x;
    const int wid = t >> 6, lane = t & 63;

    const u32* mw = (const u32*)maskv;
    int f = 0;
#pragma unroll
    for (int j = 0; j < 32; j++) f |= (mw[t * 32 + j] > 1u) ? 1 : 0;
    __shared__ int sflag[4];
    const int anyf = __any(f);
    if (lane == 0) sflag[wid] = anyf;
    __syncthreads();
    const int bytemode = sflag[0] | sflag[1] | sflag[2] | sflag[3];

    int m0, m1, m2, m3;
    if (bytemode) {
        const uchar4 mk = ((const uchar4*)((const unsigned char*)maskv + (size_t)b * 1024))[t];
        m0 = mk.x; m1 = mk.y; m2 = mk.z; m3 = mk.w;
    } else {
        const int4 mk = ((const int4*)((const int*)maskv + (size_t)b * 1024))[t];
        m0 = mk.x; m1 = mk.y; m2 = mk.z; m3 = mk.w;
    }

    const float4 sc = ((const float4*)(scores + (size_t)b * 1024))[t];
    const float v0 = m0 ? -1e30f : sc.x;
    const float v1 = m1 ? -1e30f : sc.y;
    const float v2 = m2 ? -1e30f : sc.z;
    const float v3 = m3 ? -1e30f : sc.w;
    float mx = fmaxf(fmaxf(v0, v1), fmaxf(v2, v3));
#pragma unroll
    for (int off = 1; off < 64; off <<= 1) mx = fmaxf(mx, __shfl_xor(mx, off));
    __shared__ float redm[4], reds[4];
    if (lane == 0) redm[wid] = mx;
    __syncthreads();
    mx = fmaxf(fmaxf(redm[0], redm[1]), fmaxf(redm[2], redm[3]));
    const float e0 = m0 ? 0.f : __expf(v0 - mx);
    const float e1 = m1 ? 0.f : __expf(v1 - mx);
    const float e2 = m2 ? 0.f : __expf(v2 - mx);
    const float e3 = m3 ? 0.f : __expf(v3 - mx);
    float s = e0 + e1 + e2 + e3;
#pragma unroll
    for (int off = 1; off < 64; off <<= 1) s += __shfl_xor(s, off);
    if (lane == 0) reds[wid] = s;
    __syncthreads();
    s = reds[0] + reds[1] + reds[2] + reds[3];
    const float inv = 1.f / s;
    float4 o; o.x = e0 * inv; o.y = e1 * inv; o.z = e2 * inv; o.w = e3 * inv;
    ((float4*)(out + (size_t)b * 1024))[t] = o;
}

extern "C" void kernel_launch(void* const* d_in, const int* in_sizes, int n_in,
                              void* d_out, int out_size, void* d_ws, size_t ws_size,
                              hipStream_t stream) {
    const float* hidden = (const float*)d_in[0];
    const float* enc    = (const float*)d_in[1];           // (S,B,H_IN)
    const void*  mask   = d_in[2];
    const float* W1 = (const float*)d_in[3];               // (H, H_IN+H)
    const float* b1 = (const float*)d_in[4];
    const float* W2 = (const float*)d_in[5];
    // d_in[6] = b2: softmax shift-invariant, unused.
    float* out = (float*)d_out;

    float* ws_scores = (float*)d_ws;                                   // 32768 f32
    float* ws_hv     = (float*)((char*)d_ws + 131072);                 // 32x1024 f32
    u16*   ws_Wb     = (u16*)((char*)d_ws + 262144);                   // 1024x1024 bf16 (2MB)

    hipMemsetAsync(ws_scores, 0, 32768 * sizeof(float), stream);
    pack_k<<<1024, 256, 0, stream>>>(W1, ws_Wb);
    hv_k<<<256, 256, 0, stream>>>(hidden, W1, b1, ws_hv);
    gemm_fused<<<2048, 256, 0, stream>>>(enc, ws_Wb, ws_hv, W2, ws_scores);
    softmax_k<<<32, 256, 0, stream>>>(ws_scores, mask, out);
}

// Round 3
// 130.981 us; speedup vs baseline: 1.3745x; 1.3745x over previous
//
#include <hip/hip_runtime.h>
#include <hip/hip_bf16.h>
#include <cstdint>

// Problem: B=32, S=1024, H_IN=1024, H=1024
// scores[b,s] = sum_h tanh( enc[b,s,:]·W1_enc[h,:] + hidden[b,:]·W1_hid[h,:] + b1[h] ) * W2[h]
// out[b,0,s] = softmax_s( mask ? -inf : scores )    (b2 is softmax-shift-invariant)
//
// Fast path (ws >= 68MB): mask-compact rows per batch, convert enc rows to bf16 once,
// then m97-structure GEMM (both operands via global_load_lds, single-buffered, 2-barrier)
// with fused tanh·w2 epilogue scattering into scores. ~2x less compute + no VALU convert
// in the K-loop vs round-2 kernel.

#define BM 128
#define BN 128
#define BK 64

typedef short  s16x8 __attribute__((ext_vector_type(8)));
typedef float  f32x4 __attribute__((ext_vector_type(4)));
typedef unsigned int u32;
typedef unsigned short u16;
typedef unsigned long long u64;

__device__ static inline u32 f2bf(float f) {            // f32 -> bf16 (RNE)
    u32 u = __float_as_uint(f);
    return (u + 0x7fffu + ((u >> 16) & 1u)) >> 16;
}
__device__ static inline u32 pk2(float a, float b) {    // two bf16 packed
    return f2bf(a) | (f2bf(b) << 16);
}

__device__ static inline void gload_lds16(const void* g, void* l) {
    __builtin_amdgcn_global_load_lds(
        (const __attribute__((address_space(1))) u32*)g,
        (__attribute__((address_space(3))) u32*)l, 16, 0, 0);
}

// ---------------- pack W1_enc (H x H_IN slice of W1) to bf16, linear [n][k] ----------------
__global__ __launch_bounds__(256) void pack_k(const float* __restrict__ W1, u16* __restrict__ Wb) {
    const size_t i = (size_t)blockIdx.x * 256 + threadIdx.x;   // float4 index, total 262144
    const size_t n = (i * 4) >> 10, k = (i * 4) & 1023;
    const float4 v = *(const float4*)(W1 + n * 2048 + k);
    uint2 p; p.x = pk2(v.x, v.y); p.y = pk2(v.z, v.w);
    ((uint2*)Wb)[i] = p;
}

// ---------------- hv[b][h] = hidden[b,:]·W1_hid[h,:] + b1[h]  (f32, exact) ----------------
__global__ __launch_bounds__(256) void hv_k(const float* __restrict__ hidden,
                                            const float* __restrict__ W1,
                                            const float* __restrict__ b1,
                                            float* __restrict__ hv) {
    const int wid = threadIdx.x >> 6, lane = threadIdx.x & 63;
    const int h = blockIdx.x * 4 + wid;
    const float4* wrow = (const float4*)(W1 + (size_t)h * 2048 + 1024);
    float4 w[4];
#pragma unroll
    for (int q = 0; q < 4; q++) w[q] = wrow[lane + 64 * q];
    for (int b = 0; b < 32; b++) {
        const float4* hb = (const float4*)(hidden + (size_t)b * 1024);
        float p = 0.f;
#pragma unroll
        for (int q = 0; q < 4; q++) {
            float4 x = hb[lane + 64 * q];
            p = fmaf(w[q].x, x.x, fmaf(w[q].y, x.y, fmaf(w[q].z, x.z, fmaf(w[q].w, x.w, p))));
        }
#pragma unroll
        for (int off = 1; off < 64; off <<= 1) p += __shfl_xor(p, off);
        if (lane == 0) hv[(size_t)b * 1024 + h] = p + b1[h];
    }
}

// ---------------- mask dtype detect + per-batch stable compaction of unmasked s ----------------
// one wave per batch; grid 8 x 256 threads
__global__ __launch_bounds__(256) void idx_k(const void* __restrict__ maskv,
                                             int* __restrict__ sidx,   // [32][1024]
                                             int* __restrict__ cnt) {  // [32]
    const int t = threadIdx.x, wid = t >> 6, lane = t & 63;
    // dtype detect: scan first 8192 u32 words (32KB, in-bounds either way)
    const u32* mw = (const u32*)maskv;
    int f = 0;
#pragma unroll
    for (int j = 0; j < 32; j++) f |= (mw[t * 32 + j] > 1u) ? 1 : 0;
    __shared__ int sflag[4];
    const int anyf = __any(f);
    if (lane == 0) sflag[wid] = anyf;
    __syncthreads();
    const int bytemode = sflag[0] | sflag[1] | sflag[2] | sflag[3];

    const int b = blockIdx.x * 4 + wid;
    int base = 0;
    for (int c = 0; c < 16; c++) {
        const int s = c * 64 + lane;
        int m;
        if (bytemode) m = ((const unsigned char*)maskv)[(size_t)b * 1024 + s];
        else          m = ((const int*)maskv)[(size_t)b * 1024 + s];
        const u64 bal = __ballot(m == 0);
        if (m == 0) {
            const int off = (int)__popcll(bal & ((1ull << lane) - 1ull));
            sidx[(size_t)b * 1024 + base + off] = s;
        }
        base += (int)__popcll(bal);
    }
    if (lane == 0) cnt[b] = base;
    // zero-fill padding slots (padding rows read s=0, always unmasked)
    for (int j = base + lane; j < 1024; j += 64) sidx[(size_t)b * 1024 + j] = 0;
}

// ---------------- gather-convert compacted enc rows to bf16: encC[b][j][k] ----------------
// grid (1024, 32), one block per (j, b) row
__global__ __launch_bounds__(256) void conv_k(const float* __restrict__ enc,
                                              const int* __restrict__ sidx,
                                              const int* __restrict__ cnt,
                                              u16* __restrict__ encC) {
    const int j = blockIdx.x, b = blockIdx.y, t = threadIdx.x;
    const int c = cnt[b];
    const int jmax = (c + 127) & ~127;
    if (j >= jmax) return;
    const int s = (j < c) ? sidx[(size_t)b * 1024 + j] : 0;
    const float4 v = ((const float4*)(enc + ((size_t)s * 32 + b) * 1024))[t];
    uint2 p; p.x = pk2(v.x, v.y); p.y = pk2(v.z, v.w);
    ((uint2*)(encC + ((size_t)b * 1024 + j) * 1024))[t] = p;
}

// ---------------- compacted GEMM, m97 structure: encC(128xK) x Wb^T(128xK), fused epilogue ----------------
__global__ __launch_bounds__(256, 4) void gemm_c(
    const u16* __restrict__ encC,       // [32][1024][1024] bf16 (compacted rows)
    const u16* __restrict__ Wb,         // [1024][1024] bf16
    const int* __restrict__ sidx,       // [32][1024]
    const int* __restrict__ cnt,        // [32]
    const float* __restrict__ hv,       // [32][1024] f32
    const float* __restrict__ W2,       // [1024] f32
    float*      __restrict__ scores)    // [32][1024] f32, pre-zeroed, atomic accumulate
{
    __shared__ u16 As[BM * BK];
    __shared__ u16 Bs[BN * BK];

    const int tid = threadIdx.x;
    const int bid = blockIdx.x;
    // XCD swizzle: 8 n-tiles of one m-strip share an XCD (A-strip L2 reuse)
    const int xcd = bid & 7, slot = bid >> 3;
    const int mstrip = xcd * 32 + (slot >> 3);   // 0..255
    const int nt = slot & 7;
    const int b = mstrip >> 3, mtile = mstrip & 7;
    const int c = cnt[b];
    if (mtile * 128 >= c) return;

    // staging: chunk idx = j*256+tid -> row = j*32 + (tid>>3), c16 = tid&7 (16B units)
    const int srow = tid >> 3, sc16 = tid & 7;
    const u16* asrc = encC + ((size_t)b * 1024 + mtile * 128 + srow) * 1024 + sc16 * 8;
    const u16* bsrc = Wb + ((size_t)(nt * BN) + srow) * 1024 + sc16 * 8;

    const int wid = tid >> 6, lane = tid & 63;
    const int wr = wid >> 1, wc = wid & 1;
    const int lhi = lane >> 4, llo = lane & 15;

    f32x4 acc[4][4] = {};

    for (int kt = 0; kt < 16; kt++) {
        const size_t ko = (size_t)kt * 64;
#pragma unroll
        for (int j = 0; j < 4; j++)
            gload_lds16(asrc + ko + (size_t)j * 32 * 1024, &As[(j * 256 + tid) * 8]);
#pragma unroll
        for (int j = 0; j < 4; j++)
            gload_lds16(bsrc + ko + (size_t)j * 32 * 1024, &Bs[(j * 256 + tid) * 8]);
        __syncthreads();
#pragma unroll
        for (int kk = 0; kk < 2; kk++) {
            s16x8 af[4], bfr[4];
#pragma unroll
            for (int f = 0; f < 4; f++)
                af[f] = *(const s16x8*)&As[(wr * 64 + f * 16 + llo) * BK + kk * 32 + lhi * 8];
#pragma unroll
            for (int f = 0; f < 4; f++)
                bfr[f] = *(const s16x8*)&Bs[(wc * 64 + f * 16 + llo) * BK + kk * 32 + lhi * 8];
#pragma unroll
            for (int fi = 0; fi < 4; fi++)
#pragma unroll
                for (int fj = 0; fj < 4; fj++)
                    acc[fi][fj] = __builtin_amdgcn_mfma_f32_16x16x32_bf16(af[fi], bfr[fj], acc[fi][fj], 0, 0, 0);
        }
        __syncthreads();
    }

    // epilogue: tanh(acc + hv) · w2, reduce over this block's 128 n-cols, scatter-atomic
    const float* hvb = hv + (size_t)b * 1024;
    float hvv[4], w2v[4];
#pragma unroll
    for (int fj = 0; fj < 4; fj++) {
        const int n = nt * BN + wc * 64 + fj * 16 + llo;
        hvv[fj] = hvb[n];
        w2v[fj] = W2[n];
    }
#pragma unroll
    for (int fi = 0; fi < 4; fi++) {
#pragma unroll
        for (int r = 0; r < 4; r++) {
            float sum = 0.f;
#pragma unroll
            for (int fj = 0; fj < 4; fj++) {
                const float x = acc[fi][fj][r] + hvv[fj];
                const float e = __expf(2.f * x);
                const float t = 1.f - 2.f / (e + 1.f);   // tanh(x)
                sum = fmaf(t, w2v[fj], sum);
            }
            sum += __shfl_xor(sum, 1);
            sum += __shfl_xor(sum, 2);
            sum += __shfl_xor(sum, 4);
            sum += __shfl_xor(sum, 8);
            if (llo == 0) {
                const int j = mtile * 128 + wr * 64 + fi * 16 + lhi * 4 + r;
                if (j < c) {
                    const int s = sidx[(size_t)b * 1024 + j];
                    atomicAdd(&scores[(size_t)b * 1024 + s], sum);
                }
            }
        }
    }
}

// =================== round-2 fallback GEMM (used only if ws too small) ===================
__global__ __launch_bounds__(256, 2) void gemm_fused(
    const float* __restrict__ enc, const u16* __restrict__ Wb,
    const float* __restrict__ hv, const float* __restrict__ W2,
    float* __restrict__ scores)
{
    __shared__ u16 As[2][BM * BK];
    __shared__ u16 Bs[2][BM * BK];
    const int tid = threadIdx.x;
    const int bid = blockIdx.x;
    const int xcd = bid & 7, slot = bid >> 3;
    const int mt = xcd * 32 + (slot >> 3), nt = slot & 7;
    const int b = mt >> 3;
    const int ar = tid >> 4, ac = tid & 15;
    const int s0 = ((mt & 7) << 7) + ar;
    const float4* aptr4 = (const float4*)(enc + ((size_t)s0 * 32 + b) * 1024) + ac;
    const size_t astr4 = (size_t)16 * 32 * 1024 / 4;
    const u16* wsrc = Wb + ((size_t)(nt * BN) + (tid >> 3)) * 1024 + (tid & 7) * 8;
    const int wid = tid >> 6, lane = tid & 63;
    const int wr = wid >> 1, wc = wid & 1;
    const int lhi = lane >> 4, llo = lane & 15;
    f32x4 acc[4][4] = {};
    float4 av[8];
#pragma unroll
    for (int j = 0; j < 8; j++) av[j] = aptr4[(size_t)j * astr4];
#pragma unroll
    for (int j = 0; j < 4; j++)
        gload_lds16(wsrc + (size_t)j * 32 * 1024, &Bs[0][(j * 256 + tid) * 8]);
#pragma unroll
    for (int j = 0; j < 8; j++) {
        uint2 p; p.x = pk2(av[j].x, av[j].y); p.y = pk2(av[j].z, av[j].w);
        *(uint2*)&As[0][(ar + j * 16) * BK + ac * 4] = p;
    }
    __syncthreads();
    int buf = 0;
    for (int kt = 0; kt < 16; kt++) {
        const int nk = kt + 1;
        if (nk < 16) {
#pragma unroll
            for (int j = 0; j < 8; j++) av[j] = aptr4[(size_t)j * astr4 + (size_t)nk * 16];
#pragma unroll
            for (int j = 0; j < 4; j++)
                gload_lds16(wsrc + (size_t)nk * 64 + (size_t)j * 32 * 1024,
                            &Bs[buf ^ 1][(j * 256 + tid) * 8]);
        }
#pragma unroll
        for (int kk = 0; kk < 2; kk++) {
            s16x8 af[4], bfr[4];
#pragma unroll
            for (int f = 0; f < 4; f++)
                af[f] = *(const s16x8*)&As[buf][(wr * 64 + f * 16 + llo) * BK + kk * 32 + lhi * 8];
#pragma unroll
            for (int f = 0; f < 4; f++)
                bfr[f] = *(const s16x8*)&Bs[buf][(wc * 64 + f * 16 + llo) * BK + kk * 32 + lhi * 8];
#pragma unroll
            for (int fi = 0; fi < 4; fi++)
#pragma unroll
                for (int fj = 0; fj < 4; fj++)
                    acc[fi][fj] = __builtin_amdgcn_mfma_f32_16x16x32_bf16(af[fi], bfr[fj], acc[fi][fj], 0, 0, 0);
        }
        if (nk < 16) {
#pragma unroll
            for (int j = 0; j < 8; j++) {
                uint2 p; p.x = pk2(av[j].x, av[j].y); p.y = pk2(av[j].z, av[j].w);
                *(uint2*)&As[buf ^ 1][(ar + j * 16) * BK + ac * 4] = p;
            }
        }
        __syncthreads();
        buf ^= 1;
    }
    const float* hvb = hv + (size_t)b * 1024;
    float hvv[4], w2v[4];
#pragma unroll
    for (int fj = 0; fj < 4; fj++) {
        const int n = nt * BN + wc * 64 + fj * 16 + llo;
        hvv[fj] = hvb[n];
        w2v[fj] = W2[n];
    }
#pragma unroll
    for (int fi = 0; fi < 4; fi++) {
#pragma unroll
        for (int r = 0; r < 4; r++) {
            float sum = 0.f;
#pragma unroll
            for (int fj = 0; fj < 4; fj++) {
                const float x = acc[fi][fj][r] + hvv[fj];
                const float e = __expf(2.f * x);
                const float t = 1.f - 2.f / (e + 1.f);
                sum = fmaf(t, w2v[fj], sum);
            }
            sum += __shfl_xor(sum, 1);
            sum += __shfl_xor(sum, 2);
            sum += __shfl_xor(sum, 4);
            sum += __shfl_xor(sum, 8);
            if (llo == 0)
                atomicAdd(&scores[(size_t)mt * BM + wr * 64 + fi * 16 + lhi * 4 + r], sum);
        }
    }
}

// ---------------- masked softmax per row b, mask dtype auto-detected ----------------
__global__ __launch_bounds__(256) void softmax_k(const float* __restrict__ scores,
                                                 const void* __restrict__ maskv,
                                                 float* __restrict__ out) {
    const int b = blockIdx.x, t = threadIdx.x;
    const int wid = t >> 6, lane = t & 63;
    const u32* mw = (const u32*)maskv;
    int f = 0;
#pragma unroll
    for (int j = 0; j < 32; j++) f |= (mw[t * 32 + j] > 1u) ? 1 : 0;
    __shared__ int sflag[4];
    const int anyf = __any(f);
    if (lane == 0) sflag[wid] = anyf;
    __syncthreads();
    const int bytemode = sflag[0] | sflag[1] | sflag[2] | sflag[3];

    int m0, m1, m2, m3;
    if (bytemode) {
        const uchar4 mk = ((const uchar4*)((const unsigned char*)maskv + (size_t)b * 1024))[t];
        m0 = mk.x; m1 = mk.y; m2 = mk.z; m3 = mk.w;
    } else {
        const int4 mk = ((const int4*)((const int*)maskv + (size_t)b * 1024))[t];
        m0 = mk.x; m1 = mk.y; m2 = mk.z; m3 = mk.w;
    }
    const float4 sc = ((const float4*)(scores + (size_t)b * 1024))[t];
    const float v0 = m0 ? -1e30f : sc.x;
    const float v1 = m1 ? -1e30f : sc.y;
    const float v2 = m2 ? -1e30f : sc.z;
    const float v3 = m3 ? -1e30f : sc.w;
    float mx = fmaxf(fmaxf(v0, v1), fmaxf(v2, v3));
#pragma unroll
    for (int off = 1; off < 64; off <<= 1) mx = fmaxf(mx, __shfl_xor(mx, off));
    __shared__ float redm[4], reds[4];
    if (lane == 0) redm[wid] = mx;
    __syncthreads();
    mx = fmaxf(fmaxf(redm[0], redm[1]), fmaxf(redm[2], redm[3]));
    const float e0 = m0 ? 0.f : __expf(v0 - mx);
    const float e1 = m1 ? 0.f : __expf(v1 - mx);
    const float e2 = m2 ? 0.f : __expf(v2 - mx);
    const float e3 = m3 ? 0.f : __expf(v3 - mx);
    float s = e0 + e1 + e2 + e3;
#pragma unroll
    for (int off = 1; off < 64; off <<= 1) s += __shfl_xor(s, off);
    if (lane == 0) reds[wid] = s;
    __syncthreads();
    s = reds[0] + reds[1] + reds[2] + reds[3];
    const float inv = 1.f / s;
    float4 o; o.x = e0 * inv; o.y = e1 * inv; o.z = e2 * inv; o.w = e3 * inv;
    ((float4*)(out + (size_t)b * 1024))[t] = o;
}

extern "C" void kernel_launch(void* const* d_in, const int* in_sizes, int n_in,
                              void* d_out, int out_size, void* d_ws, size_t ws_size,
                              hipStream_t stream) {
    const float* hidden = (const float*)d_in[0];
    const float* enc    = (const float*)d_in[1];           // (S,B,H_IN) f32
    const void*  mask   = d_in[2];
    const float* W1 = (const float*)d_in[3];               // (H, H_IN+H) f32
    const float* b1 = (const float*)d_in[4];
    const float* W2 = (const float*)d_in[5];
    float* out = (float*)d_out;

    char* ws = (char*)d_ws;
    float* ws_scores = (float*)ws;                          // 128 KB
    float* ws_hv     = (float*)(ws + (128u << 10));         // 128 KB
    u16*   ws_Wb     = (u16*)(ws + (256u << 10));           // 2 MB
    int*   ws_cnt    = (int*)(ws + (2304u << 10));          // 128 B
    int*   ws_sidx   = (int*)(ws + (2432u << 10));          // 128 KB
    u16*   ws_encC   = (u16*)(ws + (4096u << 10));          // 64 MB

    const bool big = ws_size >= (68ull << 20);

    hipMemsetAsync(ws_scores, 0, 32768 * sizeof(float), stream);
    pack_k<<<1024, 256, 0, stream>>>(W1, ws_Wb);
    hv_k<<<256, 256, 0, stream>>>(hidden, W1, b1, ws_hv);
    if (big) {
        idx_k<<<8, 256, 0, stream>>>(mask, ws_sidx, ws_cnt);
        conv_k<<<dim3(1024, 32), 256, 0, stream>>>(enc, ws_sidx, ws_cnt, ws_encC);
        gemm_c<<<2048, 256, 0, stream>>>(ws_encC, ws_Wb, ws_sidx, ws_cnt, ws_hv, W2, ws_scores);
    } else {
        gemm_fused<<<2048, 256, 0, stream>>>(enc, ws_Wb, ws_hv, W2, ws_scores);
    }
    softmax_k<<<32, 256, 0, stream>>>(ws_scores, mask, out);
}